// Round 20
// baseline (47.439 us; speedup 1.0000x reference)
//
#include <hip/hip_runtime.h>
#include <hip/hip_bf16.h>

#define H_ 512
#define W_ 512
#define C_ 32
#define NPOS_ (H_ * W_)
#define TX_ 32
#define TY_ 8
#define HXX_ 34
#define HYY_ 10
#define NCELL_ (HXX_ * HYY_)   // 340
#define FST_ 40                // flds stride in bf16 (80B, 16B multiple)

// cw layout (floats): Mcat[32][64]@0, U[64]@2048, PCm[64][32]@2112, R[32]@4160
#define CW_M 0
#define CW_U 2048
#define CW_P 2112
#define CW_R 4160

typedef float v2f __attribute__((ext_vector_type(2)));
typedef float f32x4_t __attribute__((ext_vector_type(4)));
typedef short bf16x8 __attribute__((ext_vector_type(8)));

static __device__ __forceinline__ v2f pk_add(v2f a, v2f b) {
    v2f d; asm("v_pk_add_f32 %0, %1, %2" : "=v"(d) : "v"(a), "v"(b)); return d;
}
static __device__ __forceinline__ v2f pk_fma(v2f a, v2f b, v2f c) {
    v2f d; asm("v_pk_fma_f32 %0, %1, %2, %3" : "=v"(d) : "v"(a), "v"(b), "v"(c)); return d;
}
static __device__ __forceinline__ unsigned cvt_pk_bf16(float lo, float hi) {
    unsigned r; asm("v_cvt_pk_bf16_f32 %0, %1, %2" : "=v"(r) : "v"(lo), "v"(hi)); return r;
}
static __device__ __forceinline__ short f2bf(float v) {
    __hip_bfloat16 h = __float2bfloat16(v);
    return *reinterpret_cast<short*>(&h);
}
// qlds addressing: row pos (64 bf16), 16B chunks XOR-swizzled by pos&7 (bank-balanced)
static __device__ __forceinline__ int q_sidx(int pos, int c) {
    return pos * 64 + ((((c >> 3) ^ (pos & 7))) << 3) + (c & 7);
}
// Wave-level LDS fence: qlds handoffs are strictly intra-wave (proven round 13).
#define WFENCE() do { asm volatile("s_waitcnt lgkmcnt(0)" ::: "memory"); \
                      __builtin_amdgcn_sched_barrier(0); } while (0)

__global__ __launch_bounds__(256) void build_grid_k(const int* __restrict__ coors,
                                                    int* __restrict__ grid, int n) {
    int i = blockIdx.x * 256 + threadIdx.x;
    if (i < n) {
        int y = coors[2 * i + 0];
        int x = coors[2 * i + 1];
        grid[y * W_ + x] = i;
    }
}

// blocks 0..255: clear full grid to -1. blocks 256..272: combined weights (green r12).
__global__ __launch_bounds__(256) void prep_k(int4* __restrict__ grid4,
                                              const float* __restrict__ wqkv,
                                              const float* __restrict__ bqkv,
                                              const float* __restrict__ wout,
                                              const float* __restrict__ bout,
                                              float* __restrict__ cw) {
    if (blockIdx.x < 256) {
        grid4[blockIdx.x * 256 + threadIdx.x] = int4{-1, -1, -1, -1};
        return;
    }
    const int e0 = (int)(blockIdx.x - 256) * 256 + threadIdx.x;
    if (e0 < 2048) {
        // Mcat[i][h*32+j] = sum_d Wq[h16+d][i] * Wk[h16+d][j]
        const int i = e0 >> 6, c = e0 & 63;
        const int h = c >> 5, j = c & 31;
        float s = 0.f;
        for (int d = 0; d < 16; ++d)
            s += wqkv[(h * 16 + d) * 32 + i] * wqkv[(32 + h * 16 + d) * 32 + j];
        cw[CW_M + e0] = s;
    } else if (e0 < 4096) {
        // PCm[h*32+j][c] = sum_d wout[c][h16+d] * Wv[h16+d][j]
        const int e = e0 - 2048;
        const int srow = e >> 5, c = e & 31;
        const int h = srow >> 5, j = srow & 31;
        float s = 0.f;
        for (int d = 0; d < 16; ++d)
            s += wout[c * 32 + h * 16 + d] * wqkv[(64 + h * 16 + d) * 32 + j];
        cw[CW_P + e] = s;
    } else if (e0 < 4160) {
        // U[h*32+j] = sum_d bq[h16+d] * Wk[h16+d][j]
        const int e = e0 - 4096;
        const int h = e >> 5, j = e & 31;
        float s = 0.f;
        for (int d = 0; d < 16; ++d)
            s += bqkv[h * 16 + d] * wqkv[(32 + h * 16 + d) * 32 + j];
        cw[CW_U + e] = s;
    } else if (e0 < 4192) {
        const int c = e0 - 4160;
        float s = bout[c];
        for (int dv = 0; dv < 32; ++dv)
            s += wout[c * 32 + dv] * bqkv[64 + dv];
        cw[CW_R + c] = s;
    }
}

__global__ __launch_bounds__(256, 2) void fused_k(const float* __restrict__ feats,
                                                  const int* __restrict__ grid,
                                                  const float* __restrict__ pe,
                                                  const float* __restrict__ cw,
                                                  float* __restrict__ canvas) {
    __shared__ __align__(16) short flds[NCELL_ * FST_];  // 27200 B
    __shared__ __align__(16) short qlds[256 * 64];       // 32768 B (qk, then g)
    __shared__ int vlds[NCELL_];                         // 1360 B
    __shared__ float pelds[288];                         // 1152 B

    const int tid = threadIdx.x;
    const int bid = blockIdx.x;
    const int tx0 = (bid & 15) * TX_;
    const int ty0 = (bid >> 4) * TY_;
    const int l15 = tid & 15;
    const int g4 = (tid >> 4) & 3;
    const int wv = tid >> 6;

    // ---- one-time weight fragments (verbatim green r12/r18) ----
    bf16x8 Bm[4];
#pragma unroll
    for (int ct = 0; ct < 4; ++ct) {
        bf16x8 b;
#pragma unroll
        for (int e = 0; e < 8; ++e)
            b[e] = f2bf(cw[CW_M + (8 * g4 + e) * 64 + ct * 16 + l15]);
        Bm[ct] = b;
    }
    bf16x8 Bp[2][2];
#pragma unroll
    for (int kc = 0; kc < 2; ++kc)
#pragma unroll
        for (int ct = 0; ct < 2; ++ct) {
            bf16x8 b;
#pragma unroll
            for (int e = 0; e < 8; ++e)
                b[e] = f2bf(cw[CW_P + (kc * 32 + 8 * g4 + e) * 32 + ct * 16 + l15]);
            Bp[kc][ct] = b;
        }
    float uq[4];
#pragma unroll
    for (int ct = 0; ct < 4; ++ct) uq[ct] = cw[CW_U + ct * 16 + l15];
    float rch[2];
#pragma unroll
    for (int ct = 0; ct < 2; ++ct) rch[ct] = cw[CW_R + ct * 16 + l15];

    // ---- stage pe + halo (2-cell branchless ILP, proven r18)
    //      + NEW (single variable this round): f32 passthrough from gather regs ----
    for (int c = tid; c < 288; c += 256) pelds[c] = pe[c];
    {
        const int c1 = tid, c2 = tid + 256;
        const int hy1 = c1 / HXX_, hx1 = c1 - hy1 * HXX_;
        const int hy2 = c2 / HXX_, hx2 = c2 - hy2 * HXX_;
        const int gy1 = ty0 + hy1 - 1, gx1 = tx0 + hx1 - 1;
        const int gy2 = ty0 + hy2 - 1, gx2 = tx0 + hx2 - 1;
        const bool ib1 = (((unsigned)gy1 < (unsigned)H_) & ((unsigned)gx1 < (unsigned)W_));
        const bool has2 = (c2 < NCELL_);
        const bool ib2 = has2 && (((unsigned)gy2 < (unsigned)H_) & ((unsigned)gx2 < (unsigned)W_));
        const int vi1 = ib1 ? grid[gy1 * W_ + gx1] : -1;
        const int vi2 = ib2 ? grid[gy2 * W_ + gx2] : -1;
        const float* s1 = feats + (size_t)(vi1 > 0 ? vi1 : 0) * 32;
        const float* s2 = feats + (size_t)(vi2 > 0 ? vi2 : 0) * 32;
        float4 A1[8], A2[8];
#pragma unroll
        for (int q = 0; q < 8; ++q) A1[q] = *reinterpret_cast<const float4*>(s1 + q * 4);
#pragma unroll
        for (int q = 0; q < 8; ++q) A2[q] = *reinterpret_cast<const float4*>(s2 + q * 4);
        vlds[c1] = vi1;
        if (has2) vlds[c2] = vi2;
        {
            const bool v1 = vi1 >= 0;
#pragma unroll
            for (int q = 0; q < 4; ++q) {
                uint4 w;
                w.x = v1 ? cvt_pk_bf16(A1[2 * q].x, A1[2 * q].y) : 0u;
                w.y = v1 ? cvt_pk_bf16(A1[2 * q].z, A1[2 * q].w) : 0u;
                w.z = v1 ? cvt_pk_bf16(A1[2 * q + 1].x, A1[2 * q + 1].y) : 0u;
                w.w = v1 ? cvt_pk_bf16(A1[2 * q + 1].z, A1[2 * q + 1].w) : 0u;
                *reinterpret_cast<uint4*>(flds + c1 * FST_ + q * 8) = w;
            }
        }
        if (has2) {
            const bool v2 = vi2 >= 0;
#pragma unroll
            for (int q = 0; q < 4; ++q) {
                uint4 w;
                w.x = v2 ? cvt_pk_bf16(A2[2 * q].x, A2[2 * q].y) : 0u;
                w.y = v2 ? cvt_pk_bf16(A2[2 * q].z, A2[2 * q].w) : 0u;
                w.z = v2 ? cvt_pk_bf16(A2[2 * q + 1].x, A2[2 * q + 1].y) : 0u;
                w.w = v2 ? cvt_pk_bf16(A2[2 * q + 1].z, A2[2 * q + 1].w) : 0u;
                *reinterpret_cast<uint4*>(flds + c2 * FST_ + q * 8) = w;
            }
        }
        // lo-plane passthrough straight from gather registers (f32 exact).
        // Interior cells (hy in [1,8], hx in [1,32]) map 1:1 to tile positions;
        // c1 covers cells 35..255, c2 covers 256..304 -> each position once.
        {
            const bool in1 = (hy1 >= 1) & (hy1 <= 8) & (hx1 >= 1) & (hx1 <= 32);
            if (in1) {
                const int p1 = gy1 * W_ + gx1;
                const float mk = vi1 >= 0 ? 1.f : 0.f;
#pragma unroll
                for (int q = 0; q < 8; ++q) {
                    canvas[(size_t)(q * 4 + 0) * NPOS_ + p1] = A1[q].x * mk;
                    canvas[(size_t)(q * 4 + 1) * NPOS_ + p1] = A1[q].y * mk;
                    canvas[(size_t)(q * 4 + 2) * NPOS_ + p1] = A1[q].z * mk;
                    canvas[(size_t)(q * 4 + 3) * NPOS_ + p1] = A1[q].w * mk;
                }
            }
            const bool in2 = has2 && ((hy2 >= 1) & (hy2 <= 8) & (hx2 >= 1) & (hx2 <= 32));
            if (in2) {
                const int p2 = gy2 * W_ + gx2;
                const float mk = vi2 >= 0 ? 1.f : 0.f;
#pragma unroll
                for (int q = 0; q < 8; ++q) {
                    canvas[(size_t)(q * 4 + 0) * NPOS_ + p2] = A2[q].x * mk;
                    canvas[(size_t)(q * 4 + 1) * NPOS_ + p2] = A2[q].y * mk;
                    canvas[(size_t)(q * 4 + 2) * NPOS_ + p2] = A2[q].z * mk;
                    canvas[(size_t)(q * 4 + 3) * NPOS_ + p2] = A2[q].w * mk;
                }
            }
        }
    }
    __syncthreads();   // block-wide: flds/vlds halo shared across waves

    // ---- QK GEMM: qk = F @ Mcat + U  (verbatim green) ----
    f32x4_t accq[4][4];
#pragma unroll
    for (int i = 0; i < 4; ++i) {
        const int rt = wv * 4 + i;
        const int pr = rt * 16 + l15;
        const int oc = ((pr >> 5) + 1) * HXX_ + (pr & 31) + 1;
        const bf16x8 af = *reinterpret_cast<const bf16x8*>(flds + oc * FST_ + 8 * g4);
#pragma unroll
        for (int ct = 0; ct < 4; ++ct) {
            f32x4_t acc = {uq[ct], uq[ct], uq[ct], uq[ct]};
            accq[i][ct] = __builtin_amdgcn_mfma_f32_16x16x32_bf16(af, Bm[ct], acc, 0, 0, 0);
        }
    }
#pragma unroll
    for (int i = 0; i < 4; ++i) {
        const int p0 = (wv * 4 + i) * 16 + g4 * 4;
#pragma unroll
        for (int ct = 0; ct < 4; ++ct) {
            const int c = ct * 16 + l15;
            const unsigned w01 = cvt_pk_bf16(accq[i][ct][0], accq[i][ct][1]);
            const unsigned w23 = cvt_pk_bf16(accq[i][ct][2], accq[i][ct][3]);
            qlds[q_sidx(p0 + 0, c)] = (short)(w01 & 0xffffu);
            qlds[q_sidx(p0 + 1, c)] = (short)(w01 >> 16);
            qlds[q_sidx(p0 + 2, c)] = (short)(w23 & 0xffffu);
            qlds[q_sidx(p0 + 3, c)] = (short)(w23 >> 16);
        }
    }
    WFENCE();   // intra-wave handoff (proven r13)

    // ---- score/softmax phase (verbatim green; lo-plane block REMOVED — it now
    //      happens during staging from registers) ----
    const int lx = tid & 31, ly = tid >> 5;
    const int pos = tid;
    const int ocell = (ly + 1) * HXX_ + lx + 1;
    const bool occ = vlds[ocell] >= 0;

    if (occ) {
        v2f qk0[16], qk1[16];
#pragma unroll
        for (int cb = 0; cb < 8; ++cb) {
            const uint4 w = *reinterpret_cast<const uint4*>(qlds + pos * 64 + ((cb ^ (pos & 7)) << 3));
            const unsigned uu[4] = {w.x, w.y, w.z, w.w};
#pragma unroll
            for (int d = 0; d < 4; ++d) {
                const int jj = cb * 4 + d;
                v2f qv;
                qv.x = __uint_as_float(uu[d] << 16);
                qv.y = __uint_as_float(uu[d] & 0xffff0000u);
                if (jj < 16) qk0[jj] = qv; else qk1[jj - 16] = qv;
            }
        }
        float l0 = 0.f, l1 = 0.f;
        v2f g0[16], g1[16];
#pragma unroll
        for (int j = 0; j < 16; ++j) { g0[j] = v2f{0.f, 0.f}; g1[j] = v2f{0.f, 0.f}; }

        const int DYv[9] = {0, -1, 1, 0, -1, 1, 0, -1, 1};
        const int DXv[9] = {0, 0, 0, 1, 1, 1, -1, -1, -1};
#pragma unroll
        for (int k = 0; k < 9; ++k) {
            const int cell = (ly + 1 + DYv[k]) * HXX_ + (lx + 1 + DXv[k]);
            const bool val = vlds[cell] >= 0;
            const short* fb = flds + cell * FST_;
            v2f t[16];
#pragma unroll
            for (int q = 0; q < 4; ++q) {
                const uint4 w = *reinterpret_cast<const uint4*>(fb + q * 8);
                const unsigned uu[4] = {w.x, w.y, w.z, w.w};
#pragma unroll
                for (int d = 0; d < 4; ++d) {
                    const int jj = q * 4 + d;
                    v2f tv;
                    tv.x = __uint_as_float(uu[d] << 16);
                    tv.y = __uint_as_float(uu[d] & 0xffff0000u);
                    t[jj] = pk_add(tv, *reinterpret_cast<const v2f*>(pelds + k * 32 + 2 * jj));
                }
            }
            v2f sp0{0.f, 0.f}, sp1{0.f, 0.f};
#pragma unroll
            for (int j = 0; j < 16; ++j) {
                sp0 = pk_fma(qk0[j], t[j], sp0);
                sp1 = pk_fma(qk1[j], t[j], sp1);
            }
            const float e0 = __expf((sp0.x + sp0.y) * 0.25f);  // scores O(0.3): no max needed
            const float e1 = __expf((sp1.x + sp1.y) * 0.25f);
            l0 += val ? e0 : 1.f;   // invalid: score 0 after uniform c-shift
            l1 += val ? e1 : 1.f;
            const float w0 = val ? e0 : 0.f;
            const float w1 = val ? e1 : 0.f;
            const v2f w0v{w0, w0}, w1v{w1, w1};
#pragma unroll
            for (int j = 0; j < 16; ++j) {
                g0[j] = pk_fma(w0v, t[j], g0[j]);
                g1[j] = pk_fma(w1v, t[j], g1[j]);
            }
        }
        const float inv0 = 1.f / l0, inv1 = 1.f / l1;
#pragma unroll
        for (int cb = 0; cb < 8; ++cb) {
            unsigned wd[4];
#pragma unroll
            for (int d = 0; d < 4; ++d) {
                const int jj = cb * 4 + d;
                const v2f gg = (jj < 16) ? g0[jj] : g1[jj - 16];
                const float iv = (jj < 16) ? inv0 : inv1;
                wd[d] = cvt_pk_bf16(gg.x * iv, gg.y * iv);
            }
            const uint4 w{wd[0], wd[1], wd[2], wd[3]};
            *reinterpret_cast<uint4*>(qlds + pos * 64 + ((cb ^ (pos & 7)) << 3)) = w;
        }
    } else {
        const uint4 z{0u, 0u, 0u, 0u};
#pragma unroll
        for (int cb = 0; cb < 8; ++cb)
            *reinterpret_cast<uint4*>(qlds + pos * 64 + ((cb ^ (pos & 7)) << 3)) = z;
    }
    WFENCE();   // intra-wave handoff (proven r13)

    // ---- OUT GEMM: out = Gcat @ PCm + R (verbatim green) ----
    f32x4_t acco[4][2];
#pragma unroll
    for (int i = 0; i < 4; ++i) {
        const int pr = (wv * 4 + i) * 16 + l15;
        const bf16x8 a0 = *reinterpret_cast<const bf16x8*>(qlds + pr * 64 + (((0 + g4) ^ (pr & 7)) << 3));
        const bf16x8 a1 = *reinterpret_cast<const bf16x8*>(qlds + pr * 64 + (((4 + g4) ^ (pr & 7)) << 3));
#pragma unroll
        for (int ct = 0; ct < 2; ++ct) {
            f32x4_t acc = {0.f, 0.f, 0.f, 0.f};
            acc = __builtin_amdgcn_mfma_f32_16x16x32_bf16(a0, Bp[0][ct], acc, 0, 0, 0);
            acc = __builtin_amdgcn_mfma_f32_16x16x32_bf16(a1, Bp[1][ct], acc, 0, 0, 0);
            acco[i][ct] = acc;
        }
    }
#pragma unroll
    for (int i = 0; i < 4; ++i) {
        const int pt0 = (wv * 4 + i) * 16 + g4 * 4;
        const int yy = pt0 >> 5, xx = pt0 & 31;
        bool ok[4];
#pragma unroll
        for (int r = 0; r < 4; ++r) {
            const int pt = pt0 + r;
            ok[r] = vlds[((pt >> 5) + 1) * HXX_ + (pt & 31) + 1] >= 0;
        }
#pragma unroll
        for (int ct = 0; ct < 2; ++ct) {
            const int ch = 32 + ct * 16 + l15;
            float4 ov;
            ov.x = ok[0] ? acco[i][ct][0] + rch[ct] : 0.f;
            ov.y = ok[1] ? acco[i][ct][1] + rch[ct] : 0.f;
            ov.z = ok[2] ? acco[i][ct][2] + rch[ct] : 0.f;
            ov.w = ok[3] ? acco[i][ct][3] + rch[ct] : 0.f;
            *reinterpret_cast<float4*>(&canvas[(size_t)ch * NPOS_ + (ty0 + yy) * W_ + tx0 + xx]) = ov;
        }
    }
}

extern "C" void kernel_launch(void* const* d_in, const int* in_sizes, int n_in,
                              void* d_out, int out_size, void* d_ws, size_t ws_size,
                              hipStream_t stream) {
    const float* feats = (const float*)d_in[0];
    const int*   coors = (const int*)d_in[1];
    const float* pe    = (const float*)d_in[2];
    const float* wqkv  = (const float*)d_in[3];
    const float* bqkv  = (const float*)d_in[4];
    const float* wout  = (const float*)d_in[5];
    const float* bout  = (const float*)d_in[6];
    float* canvas = (float*)d_out;

    const int n = in_sizes[0] / C_;                           // 200000
    int* grid = (int*)d_ws;                                   // 1 MB
    float* cw = (float*)((char*)d_ws + NPOS_ * sizeof(int));  // 4192 floats

    prep_k<<<273, 256, 0, stream>>>((int4*)grid, wqkv, bqkv, wout, bout, cw);
    build_grid_k<<<(n + 255) / 256, 256, 0, stream>>>(coors, grid, n);
    fused_k<<<(W_ / TX_) * (H_ / TY_), 256, 0, stream>>>(feats, grid, pe, cw, canvas);
}

// Round 21
// 45.297 us; speedup vs baseline: 1.0473x; 1.0473x over previous
//
#include <hip/hip_runtime.h>
#include <hip/hip_bf16.h>

#define H_ 512
#define W_ 512
#define C_ 32
#define NPOS_ (H_ * W_)
#define TX_ 32
#define TY_ 8
#define HXX_ 34
#define HYY_ 10
#define NCELL_ (HXX_ * HYY_)   // 340
#define FST_ 40                // flds stride in bf16 (80B, 16B multiple)

// cw layout (floats): Mcat[32][64]@0, U[64]@2048, PCm[64][32]@2112, R[32]@4160
#define CW_M 0
#define CW_U 2048
#define CW_P 2112
#define CW_R 4160

typedef float v2f __attribute__((ext_vector_type(2)));
typedef float f32x4_t __attribute__((ext_vector_type(4)));
typedef short bf16x8 __attribute__((ext_vector_type(8)));

static __device__ __forceinline__ v2f pk_add(v2f a, v2f b) {
    v2f d; asm("v_pk_add_f32 %0, %1, %2" : "=v"(d) : "v"(a), "v"(b)); return d;
}
static __device__ __forceinline__ v2f pk_fma(v2f a, v2f b, v2f c) {
    v2f d; asm("v_pk_fma_f32 %0, %1, %2, %3" : "=v"(d) : "v"(a), "v"(b), "v"(c)); return d;
}
static __device__ __forceinline__ unsigned cvt_pk_bf16(float lo, float hi) {
    unsigned r; asm("v_cvt_pk_bf16_f32 %0, %1, %2" : "=v"(r) : "v"(lo), "v"(hi)); return r;
}
static __device__ __forceinline__ short f2bf(float v) {
    __hip_bfloat16 h = __float2bfloat16(v);
    return *reinterpret_cast<short*>(&h);
}
// qlds addressing: row pos (64 bf16), 16B chunks XOR-swizzled by pos&7 (bank-balanced)
static __device__ __forceinline__ int q_sidx(int pos, int c) {
    return pos * 64 + ((((c >> 3) ^ (pos & 7))) << 3) + (c & 7);
}
// Wave-level LDS fence: qlds handoffs are strictly intra-wave (proven round 13).
#define WFENCE() do { asm volatile("s_waitcnt lgkmcnt(0)" ::: "memory"); \
                      __builtin_amdgcn_sched_barrier(0); } while (0)

__global__ __launch_bounds__(256) void build_grid_k(const int* __restrict__ coors,
                                                    int* __restrict__ grid, int n) {
    int i = blockIdx.x * 256 + threadIdx.x;
    if (i < n) {
        int y = coors[2 * i + 0];
        int x = coors[2 * i + 1];
        grid[y * W_ + x] = i;
    }
}

// blocks 0..255: clear full grid to -1. blocks 256..272: combined weights (green r12).
__global__ __launch_bounds__(256) void prep_k(int4* __restrict__ grid4,
                                              const float* __restrict__ wqkv,
                                              const float* __restrict__ bqkv,
                                              const float* __restrict__ wout,
                                              const float* __restrict__ bout,
                                              float* __restrict__ cw) {
    if (blockIdx.x < 256) {
        grid4[blockIdx.x * 256 + threadIdx.x] = int4{-1, -1, -1, -1};
        return;
    }
    const int e0 = (int)(blockIdx.x - 256) * 256 + threadIdx.x;
    if (e0 < 2048) {
        // Mcat[i][h*32+j] = sum_d Wq[h16+d][i] * Wk[h16+d][j]
        const int i = e0 >> 6, c = e0 & 63;
        const int h = c >> 5, j = c & 31;
        float s = 0.f;
        for (int d = 0; d < 16; ++d)
            s += wqkv[(h * 16 + d) * 32 + i] * wqkv[(32 + h * 16 + d) * 32 + j];
        cw[CW_M + e0] = s;
    } else if (e0 < 4096) {
        // PCm[h*32+j][c] = sum_d wout[c][h16+d] * Wv[h16+d][j]
        const int e = e0 - 2048;
        const int srow = e >> 5, c = e & 31;
        const int h = srow >> 5, j = srow & 31;
        float s = 0.f;
        for (int d = 0; d < 16; ++d)
            s += wout[c * 32 + h * 16 + d] * wqkv[(64 + h * 16 + d) * 32 + j];
        cw[CW_P + e] = s;
    } else if (e0 < 4160) {
        // U[h*32+j] = sum_d bq[h16+d] * Wk[h16+d][j]
        const int e = e0 - 4096;
        const int h = e >> 5, j = e & 31;
        float s = 0.f;
        for (int d = 0; d < 16; ++d)
            s += bqkv[h * 16 + d] * wqkv[(32 + h * 16 + d) * 32 + j];
        cw[CW_U + e] = s;
    } else if (e0 < 4192) {
        const int c = e0 - 4160;
        float s = bout[c];
        for (int dv = 0; dv < 32; ++dv)
            s += wout[c * 32 + dv] * bqkv[64 + dv];
        cw[CW_R + c] = s;
    }
}

__global__ __launch_bounds__(256, 2) void fused_k(const float* __restrict__ feats,
                                                  const int* __restrict__ grid,
                                                  const float* __restrict__ pe,
                                                  const float* __restrict__ cw,
                                                  float* __restrict__ canvas) {
    __shared__ __align__(16) short flds[NCELL_ * FST_];  // 27200 B
    __shared__ __align__(16) short qlds[256 * 64];       // 32768 B (qk, then g)
    __shared__ int vlds[NCELL_];                         // 1360 B
    __shared__ float pelds[288];                         // 1152 B

    const int tid = threadIdx.x;
    // XCD-aware bijective swizzle (1024 blocks = 8 XCDs x 128): each XCD owns a
    // contiguous 512x64 band -> neighboring tiles share halo rows in its L2.
    const int bid = ((int)blockIdx.x & 7) * 128 + ((int)blockIdx.x >> 3);
    const int tx0 = (bid & 15) * TX_;
    const int ty0 = (bid >> 4) * TY_;
    const int l15 = tid & 15;
    const int g4 = (tid >> 4) & 3;
    const int wv = tid >> 6;

    // ---- one-time weight fragments (verbatim green r12/r18) ----
    bf16x8 Bm[4];
#pragma unroll
    for (int ct = 0; ct < 4; ++ct) {
        bf16x8 b;
#pragma unroll
        for (int e = 0; e < 8; ++e)
            b[e] = f2bf(cw[CW_M + (8 * g4 + e) * 64 + ct * 16 + l15]);
        Bm[ct] = b;
    }
    bf16x8 Bp[2][2];
#pragma unroll
    for (int kc = 0; kc < 2; ++kc)
#pragma unroll
        for (int ct = 0; ct < 2; ++ct) {
            bf16x8 b;
#pragma unroll
            for (int e = 0; e < 8; ++e)
                b[e] = f2bf(cw[CW_P + (kc * 32 + 8 * g4 + e) * 32 + ct * 16 + l15]);
            Bp[kc][ct] = b;
        }
    float uq[4];
#pragma unroll
    for (int ct = 0; ct < 4; ++ct) uq[ct] = cw[CW_U + ct * 16 + l15];
    float rch[2];
#pragma unroll
    for (int ct = 0; ct < 2; ++ct) rch[ct] = cw[CW_R + ct * 16 + l15];

    // ---- stage pe + halo (2-cell branchless ILP, proven r18) ----
    for (int c = tid; c < 288; c += 256) pelds[c] = pe[c];
    {
        const int c1 = tid, c2 = tid + 256;
        const int hy1 = c1 / HXX_, hx1 = c1 - hy1 * HXX_;
        const int hy2 = c2 / HXX_, hx2 = c2 - hy2 * HXX_;
        const int gy1 = ty0 + hy1 - 1, gx1 = tx0 + hx1 - 1;
        const int gy2 = ty0 + hy2 - 1, gx2 = tx0 + hx2 - 1;
        const bool ib1 = (((unsigned)gy1 < (unsigned)H_) & ((unsigned)gx1 < (unsigned)W_));
        const bool has2 = (c2 < NCELL_);
        const bool ib2 = has2 && (((unsigned)gy2 < (unsigned)H_) & ((unsigned)gx2 < (unsigned)W_));
        const int vi1 = ib1 ? grid[gy1 * W_ + gx1] : -1;
        const int vi2 = ib2 ? grid[gy2 * W_ + gx2] : -1;
        const float* s1 = feats + (size_t)(vi1 > 0 ? vi1 : 0) * 32;
        const float* s2 = feats + (size_t)(vi2 > 0 ? vi2 : 0) * 32;
        float4 A1[8], A2[8];
#pragma unroll
        for (int q = 0; q < 8; ++q) A1[q] = *reinterpret_cast<const float4*>(s1 + q * 4);
#pragma unroll
        for (int q = 0; q < 8; ++q) A2[q] = *reinterpret_cast<const float4*>(s2 + q * 4);
        vlds[c1] = vi1;
        if (has2) vlds[c2] = vi2;
        {
            const bool v1 = vi1 >= 0;
#pragma unroll
            for (int q = 0; q < 4; ++q) {
                uint4 w;
                w.x = v1 ? cvt_pk_bf16(A1[2 * q].x, A1[2 * q].y) : 0u;
                w.y = v1 ? cvt_pk_bf16(A1[2 * q].z, A1[2 * q].w) : 0u;
                w.z = v1 ? cvt_pk_bf16(A1[2 * q + 1].x, A1[2 * q + 1].y) : 0u;
                w.w = v1 ? cvt_pk_bf16(A1[2 * q + 1].z, A1[2 * q + 1].w) : 0u;
                *reinterpret_cast<uint4*>(flds + c1 * FST_ + q * 8) = w;
            }
        }
        if (has2) {
            const bool v2 = vi2 >= 0;
#pragma unroll
            for (int q = 0; q < 4; ++q) {
                uint4 w;
                w.x = v2 ? cvt_pk_bf16(A2[2 * q].x, A2[2 * q].y) : 0u;
                w.y = v2 ? cvt_pk_bf16(A2[2 * q].z, A2[2 * q].w) : 0u;
                w.z = v2 ? cvt_pk_bf16(A2[2 * q + 1].x, A2[2 * q + 1].y) : 0u;
                w.w = v2 ? cvt_pk_bf16(A2[2 * q + 1].z, A2[2 * q + 1].w) : 0u;
                *reinterpret_cast<uint4*>(flds + c2 * FST_ + q * 8) = w;
            }
        }
    }
    __syncthreads();   // block-wide: flds/vlds halo shared across waves

    // ---- QK GEMM: qk = F @ Mcat + U  (verbatim green) ----
    f32x4_t accq[4][4];
#pragma unroll
    for (int i = 0; i < 4; ++i) {
        const int rt = wv * 4 + i;
        const int pr = rt * 16 + l15;
        const int oc = ((pr >> 5) + 1) * HXX_ + (pr & 31) + 1;
        const bf16x8 af = *reinterpret_cast<const bf16x8*>(flds + oc * FST_ + 8 * g4);
#pragma unroll
        for (int ct = 0; ct < 4; ++ct) {
            f32x4_t acc = {uq[ct], uq[ct], uq[ct], uq[ct]};
            accq[i][ct] = __builtin_amdgcn_mfma_f32_16x16x32_bf16(af, Bm[ct], acc, 0, 0, 0);
        }
    }
#pragma unroll
    for (int i = 0; i < 4; ++i) {
        const int p0 = (wv * 4 + i) * 16 + g4 * 4;
#pragma unroll
        for (int ct = 0; ct < 4; ++ct) {
            const int c = ct * 16 + l15;
            const unsigned w01 = cvt_pk_bf16(accq[i][ct][0], accq[i][ct][1]);
            const unsigned w23 = cvt_pk_bf16(accq[i][ct][2], accq[i][ct][3]);
            qlds[q_sidx(p0 + 0, c)] = (short)(w01 & 0xffffu);
            qlds[q_sidx(p0 + 1, c)] = (short)(w01 >> 16);
            qlds[q_sidx(p0 + 2, c)] = (short)(w23 & 0xffffu);
            qlds[q_sidx(p0 + 3, c)] = (short)(w23 >> 16);
        }
    }
    WFENCE();   // intra-wave handoff (proven r13)

    // ---- score/softmax phase (green body; split dot chains this round) ----
    const int lx = tid & 31, ly = tid >> 5;
    const int p = (ty0 + ly) * W_ + tx0 + lx;
    const int pos = tid;
    const int ocell = (ly + 1) * HXX_ + lx + 1;
    const bool occ = vlds[ocell] >= 0;

    // lo planes (bf16-rounded passthrough from flds; verbatim green/r18)
    {
        const short* fb = flds + ocell * FST_;
#pragma unroll
        for (int q = 0; q < 4; ++q) {
            const uint4 w = *reinterpret_cast<const uint4*>(fb + q * 8);
            const unsigned uu[4] = {w.x, w.y, w.z, w.w};
#pragma unroll
            for (int d = 0; d < 4; ++d) {
                const int j = q * 8 + d * 2;
                canvas[(size_t)j * NPOS_ + p] = __uint_as_float(uu[d] << 16);
                canvas[(size_t)(j + 1) * NPOS_ + p] = __uint_as_float(uu[d] & 0xffff0000u);
            }
        }
    }

    if (occ) {
        v2f qk0[16], qk1[16];
#pragma unroll
        for (int cb = 0; cb < 8; ++cb) {
            const uint4 w = *reinterpret_cast<const uint4*>(qlds + pos * 64 + ((cb ^ (pos & 7)) << 3));
            const unsigned uu[4] = {w.x, w.y, w.z, w.w};
#pragma unroll
            for (int d = 0; d < 4; ++d) {
                const int jj = cb * 4 + d;
                v2f qv;
                qv.x = __uint_as_float(uu[d] << 16);
                qv.y = __uint_as_float(uu[d] & 0xffff0000u);
                if (jj < 16) qk0[jj] = qv; else qk1[jj - 16] = qv;
            }
        }
        float l0 = 0.f, l1 = 0.f;
        v2f g0[16], g1[16];
#pragma unroll
        for (int j = 0; j < 16; ++j) { g0[j] = v2f{0.f, 0.f}; g1[j] = v2f{0.f, 0.f}; }

        const int DYv[9] = {0, -1, 1, 0, -1, 1, 0, -1, 1};
        const int DXv[9] = {0, 0, 0, 1, 1, 1, -1, -1, -1};
#pragma unroll
        for (int k = 0; k < 9; ++k) {
            const int cell = (ly + 1 + DYv[k]) * HXX_ + (lx + 1 + DXv[k]);
            const bool val = vlds[cell] >= 0;
            const short* fb = flds + cell * FST_;
            v2f t[16];
#pragma unroll
            for (int q = 0; q < 4; ++q) {
                const uint4 w = *reinterpret_cast<const uint4*>(fb + q * 8);
                const unsigned uu[4] = {w.x, w.y, w.z, w.w};
#pragma unroll
                for (int d = 0; d < 4; ++d) {
                    const int jj = q * 4 + d;
                    v2f tv;
                    tv.x = __uint_as_float(uu[d] << 16);
                    tv.y = __uint_as_float(uu[d] & 0xffff0000u);
                    t[jj] = pk_add(tv, *reinterpret_cast<const v2f*>(pelds + k * 32 + 2 * jj));
                }
            }
            // split dot chains: 2 accumulators per head (dep chain 16 -> 8)
            v2f sa0{0.f, 0.f}, sb0{0.f, 0.f}, sa1{0.f, 0.f}, sb1{0.f, 0.f};
#pragma unroll
            for (int j = 0; j < 8; ++j) {
                sa0 = pk_fma(qk0[j], t[j], sa0);
                sa1 = pk_fma(qk1[j], t[j], sa1);
            }
#pragma unroll
            for (int j = 8; j < 16; ++j) {
                sb0 = pk_fma(qk0[j], t[j], sb0);
                sb1 = pk_fma(qk1[j], t[j], sb1);
            }
            const float e0 = __expf((sa0.x + sa0.y + sb0.x + sb0.y) * 0.25f);
            const float e1 = __expf((sa1.x + sa1.y + sb1.x + sb1.y) * 0.25f);
            l0 += val ? e0 : 1.f;   // invalid: score 0 after uniform c-shift
            l1 += val ? e1 : 1.f;
            const float w0 = val ? e0 : 0.f;
            const float w1 = val ? e1 : 0.f;
            const v2f w0v{w0, w0}, w1v{w1, w1};
#pragma unroll
            for (int j = 0; j < 16; ++j) {
                g0[j] = pk_fma(w0v, t[j], g0[j]);
                g1[j] = pk_fma(w1v, t[j], g1[j]);
            }
        }
        const float inv0 = 1.f / l0, inv1 = 1.f / l1;
#pragma unroll
        for (int cb = 0; cb < 8; ++cb) {
            unsigned wd[4];
#pragma unroll
            for (int d = 0; d < 4; ++d) {
                const int jj = cb * 4 + d;
                const v2f gg = (jj < 16) ? g0[jj] : g1[jj - 16];
                const float iv = (jj < 16) ? inv0 : inv1;
                wd[d] = cvt_pk_bf16(gg.x * iv, gg.y * iv);
            }
            const uint4 w{wd[0], wd[1], wd[2], wd[3]};
            *reinterpret_cast<uint4*>(qlds + pos * 64 + ((cb ^ (pos & 7)) << 3)) = w;
        }
    } else {
        const uint4 z{0u, 0u, 0u, 0u};
#pragma unroll
        for (int cb = 0; cb < 8; ++cb)
            *reinterpret_cast<uint4*>(qlds + pos * 64 + ((cb ^ (pos & 7)) << 3)) = z;
    }
    WFENCE();   // intra-wave handoff (proven r13)

    // ---- OUT GEMM: out = Gcat @ PCm + R (verbatim green) ----
    f32x4_t acco[4][2];
#pragma unroll
    for (int i = 0; i < 4; ++i) {
        const int pr = (wv * 4 + i) * 16 + l15;
        const bf16x8 a0 = *reinterpret_cast<const bf16x8*>(qlds + pr * 64 + (((0 + g4) ^ (pr & 7)) << 3));
        const bf16x8 a1 = *reinterpret_cast<const bf16x8*>(qlds + pr * 64 + (((4 + g4) ^ (pr & 7)) << 3));
#pragma unroll
        for (int ct = 0; ct < 2; ++ct) {
            f32x4_t acc = {0.f, 0.f, 0.f, 0.f};
            acc = __builtin_amdgcn_mfma_f32_16x16x32_bf16(a0, Bp[0][ct], acc, 0, 0, 0);
            acc = __builtin_amdgcn_mfma_f32_16x16x32_bf16(a1, Bp[1][ct], acc, 0, 0, 0);
            acco[i][ct] = acc;
        }
    }
#pragma unroll
    for (int i = 0; i < 4; ++i) {
        const int pt0 = (wv * 4 + i) * 16 + g4 * 4;
        const int yy = pt0 >> 5, xx = pt0 & 31;
        bool ok[4];
#pragma unroll
        for (int r = 0; r < 4; ++r) {
            const int pt = pt0 + r;
            ok[r] = vlds[((pt >> 5) + 1) * HXX_ + (pt & 31) + 1] >= 0;
        }
#pragma unroll
        for (int ct = 0; ct < 2; ++ct) {
            const int ch = 32 + ct * 16 + l15;
            float4 ov;
            ov.x = ok[0] ? acco[i][ct][0] + rch[ct] : 0.f;
            ov.y = ok[1] ? acco[i][ct][1] + rch[ct] : 0.f;
            ov.z = ok[2] ? acco[i][ct][2] + rch[ct] : 0.f;
            ov.w = ok[3] ? acco[i][ct][3] + rch[ct] : 0.f;
            *reinterpret_cast<float4*>(&canvas[(size_t)ch * NPOS_ + (ty0 + yy) * W_ + tx0 + xx]) = ov;
        }
    }
}

extern "C" void kernel_launch(void* const* d_in, const int* in_sizes, int n_in,
                              void* d_out, int out_size, void* d_ws, size_t ws_size,
                              hipStream_t stream) {
    const float* feats = (const float*)d_in[0];
    const int*   coors = (const int*)d_in[1];
    const float* pe    = (const float*)d_in[2];
    const float* wqkv  = (const float*)d_in[3];
    const float* bqkv  = (const float*)d_in[4];
    const float* wout  = (const float*)d_in[5];
    const float* bout  = (const float*)d_in[6];
    float* canvas = (float*)d_out;

    const int n = in_sizes[0] / C_;                           // 200000
    int* grid = (int*)d_ws;                                   // 1 MB
    float* cw = (float*)((char*)d_ws + NPOS_ * sizeof(int));  // 4192 floats

    prep_k<<<273, 256, 0, stream>>>((int4*)grid, wqkv, bqkv, wout, bout, cw);
    build_grid_k<<<(n + 255) / 256, 256, 0, stream>>>(coors, grid, n);
    fused_k<<<(W_ / TX_) * (H_ / TY_), 256, 0, stream>>>(feats, grid, pe, cw, canvas);
}

// Round 25
// 44.871 us; speedup vs baseline: 1.0572x; 1.0095x over previous
//
#include <hip/hip_runtime.h>
#include <hip/hip_bf16.h>

#define H_ 512
#define W_ 512
#define C_ 32
#define NPOS_ (H_ * W_)
#define TX_ 32
#define TY_ 8
#define HXX_ 34
#define HYY_ 10
#define NCELL_ (HXX_ * HYY_)   // 340
#define FST_ 40                // flds stride in bf16 (80B, 16B multiple)

// cw layout (floats): Mcat[32][64]@0, U[64]@2048, PCm[64][32]@2112, R[32]@4160
#define CW_M 0
#define CW_U 2048
#define CW_P 2112
#define CW_R 4160

typedef float v2f __attribute__((ext_vector_type(2)));
typedef float f32x4_t __attribute__((ext_vector_type(4)));
typedef short bf16x8 __attribute__((ext_vector_type(8)));

static __device__ __forceinline__ v2f pk_add(v2f a, v2f b) {
    v2f d; asm("v_pk_add_f32 %0, %1, %2" : "=v"(d) : "v"(a), "v"(b)); return d;
}
static __device__ __forceinline__ v2f pk_fma(v2f a, v2f b, v2f c) {
    v2f d; asm("v_pk_fma_f32 %0, %1, %2, %3" : "=v"(d) : "v"(a), "v"(b), "v"(c)); return d;
}
static __device__ __forceinline__ unsigned cvt_pk_bf16(float lo, float hi) {
    unsigned r; asm("v_cvt_pk_bf16_f32 %0, %1, %2" : "=v"(r) : "v"(lo), "v"(hi)); return r;
}
static __device__ __forceinline__ short f2bf(float v) {
    __hip_bfloat16 h = __float2bfloat16(v);
    return *reinterpret_cast<short*>(&h);
}
// qlds addressing: row pos (64 bf16), 16B chunks XOR-swizzled by pos&7 (bank-balanced)
static __device__ __forceinline__ int q_sidx(int pos, int c) {
    return pos * 64 + ((((c >> 3) ^ (pos & 7))) << 3) + (c & 7);
}
// Wave-level LDS fence: qlds handoffs are strictly intra-wave (proven round 13).
#define WFENCE() do { asm volatile("s_waitcnt lgkmcnt(0)" ::: "memory"); \
                      __builtin_amdgcn_sched_barrier(0); } while (0)

__global__ __launch_bounds__(256) void build_grid_k(const int* __restrict__ coors,
                                                    int* __restrict__ grid, int n) {
    int i = blockIdx.x * 256 + threadIdx.x;
    if (i < n) {
        int y = coors[2 * i + 0];
        int x = coors[2 * i + 1];
        grid[y * W_ + x] = i;
    }
}

// blocks 0..255: clear full grid to -1. blocks 256..272: combined weights (green r12).
__global__ __launch_bounds__(256) void prep_k(int4* __restrict__ grid4,
                                              const float* __restrict__ wqkv,
                                              const float* __restrict__ bqkv,
                                              const float* __restrict__ wout,
                                              const float* __restrict__ bout,
                                              float* __restrict__ cw) {
    if (blockIdx.x < 256) {
        grid4[blockIdx.x * 256 + threadIdx.x] = int4{-1, -1, -1, -1};
        return;
    }
    const int e0 = (int)(blockIdx.x - 256) * 256 + threadIdx.x;
    if (e0 < 2048) {
        // Mcat[i][h*32+j] = sum_d Wq[h16+d][i] * Wk[h16+d][j]
        const int i = e0 >> 6, c = e0 & 63;
        const int h = c >> 5, j = c & 31;
        float s = 0.f;
        for (int d = 0; d < 16; ++d)
            s += wqkv[(h * 16 + d) * 32 + i] * wqkv[(32 + h * 16 + d) * 32 + j];
        cw[CW_M + e0] = s;
    } else if (e0 < 4096) {
        // PCm[h*32+j][c] = sum_d wout[c][h16+d] * Wv[h16+d][j]
        const int e = e0 - 2048;
        const int srow = e >> 5, c = e & 31;
        const int h = srow >> 5, j = srow & 31;
        float s = 0.f;
        for (int d = 0; d < 16; ++d)
            s += wout[c * 32 + h * 16 + d] * wqkv[(64 + h * 16 + d) * 32 + j];
        cw[CW_P + e] = s;
    } else if (e0 < 4160) {
        // U[h*32+j] = sum_d bq[h16+d] * Wk[h16+d][j]
        const int e = e0 - 4096;
        const int h = e >> 5, j = e & 31;
        float s = 0.f;
        for (int d = 0; d < 16; ++d)
            s += bqkv[h * 16 + d] * wqkv[(32 + h * 16 + d) * 32 + j];
        cw[CW_U + e] = s;
    } else if (e0 < 4192) {
        const int c = e0 - 4160;
        float s = bout[c];
        for (int dv = 0; dv < 32; ++dv)
            s += wout[c * 32 + dv] * bqkv[64 + dv];
        cw[CW_R + c] = s;
    }
}

__global__ __launch_bounds__(256, 2) void fused_k(const float* __restrict__ feats,
                                                  const int* __restrict__ grid,
                                                  const float* __restrict__ pe,
                                                  const float* __restrict__ cw,
                                                  float* __restrict__ canvas) {
    __shared__ __align__(16) short flds[NCELL_ * FST_];  // 27200 B
    __shared__ __align__(16) short qlds[256 * 64];       // 32768 B (qk, then g)
    __shared__ int vlds[NCELL_];                         // 1360 B
    __shared__ float pelds[288];                         // 1152 B

    const int tid = threadIdx.x;
    // XCD-aware bijective swizzle (1024 blocks = 8 XCDs x 128): each XCD owns a
    // contiguous 512x64 band -> neighboring tiles share halo rows in its L2.
    const int bid = ((int)blockIdx.x & 7) * 128 + ((int)blockIdx.x >> 3);
    const int tx0 = (bid & 15) * TX_;
    const int ty0 = (bid >> 4) * TY_;
    const int l15 = tid & 15;
    const int g4 = (tid >> 4) & 3;
    const int wv = tid >> 6;

    // ---- one-time weight fragments (verbatim green r12/r18) ----
    bf16x8 Bm[4];
#pragma unroll
    for (int ct = 0; ct < 4; ++ct) {
        bf16x8 b;
#pragma unroll
        for (int e = 0; e < 8; ++e)
            b[e] = f2bf(cw[CW_M + (8 * g4 + e) * 64 + ct * 16 + l15]);
        Bm[ct] = b;
    }
    bf16x8 Bp[2][2];
#pragma unroll
    for (int kc = 0; kc < 2; ++kc)
#pragma unroll
        for (int ct = 0; ct < 2; ++ct) {
            bf16x8 b;
#pragma unroll
            for (int e = 0; e < 8; ++e)
                b[e] = f2bf(cw[CW_P + (kc * 32 + 8 * g4 + e) * 32 + ct * 16 + l15]);
            Bp[kc][ct] = b;
        }
    float uq[4];
#pragma unroll
    for (int ct = 0; ct < 4; ++ct) uq[ct] = cw[CW_U + ct * 16 + l15];
    float rch[2];
#pragma unroll
    for (int ct = 0; ct < 2; ++ct) rch[ct] = cw[CW_R + ct * 16 + l15];

    // ---- stage pe + halo (2-cell branchless ILP, proven r18) ----
    for (int c = tid; c < 288; c += 256) pelds[c] = pe[c];
    {
        const int c1 = tid, c2 = tid + 256;
        const int hy1 = c1 / HXX_, hx1 = c1 - hy1 * HXX_;
        const int hy2 = c2 / HXX_, hx2 = c2 - hy2 * HXX_;
        const int gy1 = ty0 + hy1 - 1, gx1 = tx0 + hx1 - 1;
        const int gy2 = ty0 + hy2 - 1, gx2 = tx0 + hx2 - 1;
        const bool ib1 = (((unsigned)gy1 < (unsigned)H_) & ((unsigned)gx1 < (unsigned)W_));
        const bool has2 = (c2 < NCELL_);
        const bool ib2 = has2 && (((unsigned)gy2 < (unsigned)H_) & ((unsigned)gx2 < (unsigned)W_));
        const int vi1 = ib1 ? grid[gy1 * W_ + gx1] : -1;
        const int vi2 = ib2 ? grid[gy2 * W_ + gx2] : -1;
        const float* s1 = feats + (size_t)(vi1 > 0 ? vi1 : 0) * 32;
        const float* s2 = feats + (size_t)(vi2 > 0 ? vi2 : 0) * 32;
        float4 A1[8], A2[8];
#pragma unroll
        for (int q = 0; q < 8; ++q) A1[q] = *reinterpret_cast<const float4*>(s1 + q * 4);
#pragma unroll
        for (int q = 0; q < 8; ++q) A2[q] = *reinterpret_cast<const float4*>(s2 + q * 4);
        vlds[c1] = vi1;
        if (has2) vlds[c2] = vi2;
        {
            const bool v1 = vi1 >= 0;
#pragma unroll
            for (int q = 0; q < 4; ++q) {
                uint4 w;
                w.x = v1 ? cvt_pk_bf16(A1[2 * q].x, A1[2 * q].y) : 0u;
                w.y = v1 ? cvt_pk_bf16(A1[2 * q].z, A1[2 * q].w) : 0u;
                w.z = v1 ? cvt_pk_bf16(A1[2 * q + 1].x, A1[2 * q + 1].y) : 0u;
                w.w = v1 ? cvt_pk_bf16(A1[2 * q + 1].z, A1[2 * q + 1].w) : 0u;
                *reinterpret_cast<uint4*>(flds + c1 * FST_ + q * 8) = w;
            }
        }
        if (has2) {
            const bool v2 = vi2 >= 0;
#pragma unroll
            for (int q = 0; q < 4; ++q) {
                uint4 w;
                w.x = v2 ? cvt_pk_bf16(A2[2 * q].x, A2[2 * q].y) : 0u;
                w.y = v2 ? cvt_pk_bf16(A2[2 * q].z, A2[2 * q].w) : 0u;
                w.z = v2 ? cvt_pk_bf16(A2[2 * q + 1].x, A2[2 * q + 1].y) : 0u;
                w.w = v2 ? cvt_pk_bf16(A2[2 * q + 1].z, A2[2 * q + 1].w) : 0u;
                *reinterpret_cast<uint4*>(flds + c2 * FST_ + q * 8) = w;
            }
        }
    }
    __syncthreads();   // block-wide: flds/vlds halo shared across waves

    // ---- QK GEMM: qk = F @ Mcat + U  (verbatim green) ----
    f32x4_t accq[4][4];
#pragma unroll
    for (int i = 0; i < 4; ++i) {
        const int rt = wv * 4 + i;
        const int pr = rt * 16 + l15;
        const int oc = ((pr >> 5) + 1) * HXX_ + (pr & 31) + 1;
        const bf16x8 af = *reinterpret_cast<const bf16x8*>(flds + oc * FST_ + 8 * g4);
#pragma unroll
        for (int ct = 0; ct < 4; ++ct) {
            f32x4_t acc = {uq[ct], uq[ct], uq[ct], uq[ct]};
            accq[i][ct] = __builtin_amdgcn_mfma_f32_16x16x32_bf16(af, Bm[ct], acc, 0, 0, 0);
        }
    }
#pragma unroll
    for (int i = 0; i < 4; ++i) {
        const int p0 = (wv * 4 + i) * 16 + g4 * 4;
#pragma unroll
        for (int ct = 0; ct < 4; ++ct) {
            const int c = ct * 16 + l15;
            const unsigned w01 = cvt_pk_bf16(accq[i][ct][0], accq[i][ct][1]);
            const unsigned w23 = cvt_pk_bf16(accq[i][ct][2], accq[i][ct][3]);
            qlds[q_sidx(p0 + 0, c)] = (short)(w01 & 0xffffu);
            qlds[q_sidx(p0 + 1, c)] = (short)(w01 >> 16);
            qlds[q_sidx(p0 + 2, c)] = (short)(w23 & 0xffffu);
            qlds[q_sidx(p0 + 3, c)] = (short)(w23 >> 16);
        }
    }
    WFENCE();   // intra-wave handoff (proven r13)

    // ---- score/softmax phase (green body; split dot chains, proven r21) ----
    const int lx = tid & 31, ly = tid >> 5;
    const int p = (ty0 + ly) * W_ + tx0 + lx;
    const int pos = tid;
    const int ocell = (ly + 1) * HXX_ + lx + 1;
    const bool occ = vlds[ocell] >= 0;

    // lo planes (bf16-rounded passthrough from flds; verbatim green/r18)
    {
        const short* fb = flds + ocell * FST_;
#pragma unroll
        for (int q = 0; q < 4; ++q) {
            const uint4 w = *reinterpret_cast<const uint4*>(fb + q * 8);
            const unsigned uu[4] = {w.x, w.y, w.z, w.w};
#pragma unroll
            for (int d = 0; d < 4; ++d) {
                const int j = q * 8 + d * 2;
                canvas[(size_t)j * NPOS_ + p] = __uint_as_float(uu[d] << 16);
                canvas[(size_t)(j + 1) * NPOS_ + p] = __uint_as_float(uu[d] & 0xffff0000u);
            }
        }
    }

    if (occ) {
        v2f qk0[16], qk1[16];
#pragma unroll
        for (int cb = 0; cb < 8; ++cb) {
            const uint4 w = *reinterpret_cast<const uint4*>(qlds + pos * 64 + ((cb ^ (pos & 7)) << 3));
            const unsigned uu[4] = {w.x, w.y, w.z, w.w};
#pragma unroll
            for (int d = 0; d < 4; ++d) {
                const int jj = cb * 4 + d;
                v2f qv;
                qv.x = __uint_as_float(uu[d] << 16);
                qv.y = __uint_as_float(uu[d] & 0xffff0000u);
                if (jj < 16) qk0[jj] = qv; else qk1[jj - 16] = qv;
            }
        }
        float l0 = 0.f, l1 = 0.f;
        v2f g0[16], g1[16];
#pragma unroll
        for (int j = 0; j < 16; ++j) { g0[j] = v2f{0.f, 0.f}; g1[j] = v2f{0.f, 0.f}; }

        const int DYv[9] = {0, -1, 1, 0, -1, 1, 0, -1, 1};
        const int DXv[9] = {0, 0, 0, 1, 1, 1, -1, -1, -1};
#pragma unroll
        for (int k = 0; k < 9; ++k) {
            const int cell = (ly + 1 + DYv[k]) * HXX_ + (lx + 1 + DXv[k]);
            const bool val = vlds[cell] >= 0;
            const short* fb = flds + cell * FST_;
            v2f t[16];
#pragma unroll
            for (int q = 0; q < 4; ++q) {
                const uint4 w = *reinterpret_cast<const uint4*>(fb + q * 8);
                const unsigned uu[4] = {w.x, w.y, w.z, w.w};
#pragma unroll
                for (int d = 0; d < 4; ++d) {
                    const int jj = q * 4 + d;
                    v2f tv;
                    tv.x = __uint_as_float(uu[d] << 16);
                    tv.y = __uint_as_float(uu[d] & 0xffff0000u);
                    t[jj] = pk_add(tv, *reinterpret_cast<const v2f*>(pelds + k * 32 + 2 * jj));
                }
            }
            // split dot chains: 2 accumulators per head (dep chain 16 -> 8)
            v2f sa0{0.f, 0.f}, sb0{0.f, 0.f}, sa1{0.f, 0.f}, sb1{0.f, 0.f};
#pragma unroll
            for (int j = 0; j < 8; ++j) {
                sa0 = pk_fma(qk0[j], t[j], sa0);
                sa1 = pk_fma(qk1[j], t[j], sa1);
            }
#pragma unroll
            for (int j = 8; j < 16; ++j) {
                sb0 = pk_fma(qk0[j], t[j], sb0);
                sb1 = pk_fma(qk1[j], t[j], sb1);
            }
            const float e0 = __expf((sa0.x + sa0.y + sb0.x + sb0.y) * 0.25f);
            const float e1 = __expf((sa1.x + sa1.y + sb1.x + sb1.y) * 0.25f);
            l0 += val ? e0 : 1.f;   // invalid: score 0 after uniform c-shift
            l1 += val ? e1 : 1.f;
            const float w0 = val ? e0 : 0.f;
            const float w1 = val ? e1 : 0.f;
            const v2f w0v{w0, w0}, w1v{w1, w1};
#pragma unroll
            for (int j = 0; j < 16; ++j) {
                g0[j] = pk_fma(w0v, t[j], g0[j]);
                g1[j] = pk_fma(w1v, t[j], g1[j]);
            }
        }
        const float inv0 = 1.f / l0, inv1 = 1.f / l1;
#pragma unroll
        for (int cb = 0; cb < 8; ++cb) {
            unsigned wd[4];
#pragma unroll
            for (int d = 0; d < 4; ++d) {
                const int jj = cb * 4 + d;
                const v2f gg = (jj < 16) ? g0[jj] : g1[jj - 16];
                const float iv = (jj < 16) ? inv0 : inv1;
                wd[d] = cvt_pk_bf16(gg.x * iv, gg.y * iv);
            }
            const uint4 w{wd[0], wd[1], wd[2], wd[3]};
            *reinterpret_cast<uint4*>(qlds + pos * 64 + ((cb ^ (pos & 7)) << 3)) = w;
        }
    } else {
        const uint4 z{0u, 0u, 0u, 0u};
#pragma unroll
        for (int cb = 0; cb < 8; ++cb)
            *reinterpret_cast<uint4*>(qlds + pos * 64 + ((cb ^ (pos & 7)) << 3)) = z;
    }
    WFENCE();   // intra-wave handoff (proven r13)

    // ---- OUT GEMM: out = Gcat @ PCm + R (verbatim green) ----
    f32x4_t acco[4][2];
#pragma unroll
    for (int i = 0; i < 4; ++i) {
        const int pr = (wv * 4 + i) * 16 + l15;
        const bf16x8 a0 = *reinterpret_cast<const bf16x8*>(qlds + pr * 64 + (((0 + g4) ^ (pr & 7)) << 3));
        const bf16x8 a1 = *reinterpret_cast<const bf16x8*>(qlds + pr * 64 + (((4 + g4) ^ (pr & 7)) << 3));
#pragma unroll
        for (int ct = 0; ct < 2; ++ct) {
            f32x4_t acc = {0.f, 0.f, 0.f, 0.f};
            acc = __builtin_amdgcn_mfma_f32_16x16x32_bf16(a0, Bp[0][ct], acc, 0, 0, 0);
            acc = __builtin_amdgcn_mfma_f32_16x16x32_bf16(a1, Bp[1][ct], acc, 0, 0, 0);
            acco[i][ct] = acc;
        }
    }
#pragma unroll
    for (int i = 0; i < 4; ++i) {
        const int pt0 = (wv * 4 + i) * 16 + g4 * 4;
        const int yy = pt0 >> 5, xx = pt0 & 31;
        bool ok[4];
#pragma unroll
        for (int r = 0; r < 4; ++r) {
            const int pt = pt0 + r;
            ok[r] = vlds[((pt >> 5) + 1) * HXX_ + (pt & 31) + 1] >= 0;
        }
#pragma unroll
        for (int ct = 0; ct < 2; ++ct) {
            const int ch = 32 + ct * 16 + l15;
            float4 ov;
            ov.x = ok[0] ? acco[i][ct][0] + rch[ct] : 0.f;
            ov.y = ok[1] ? acco[i][ct][1] + rch[ct] : 0.f;
            ov.z = ok[2] ? acco[i][ct][2] + rch[ct] : 0.f;
            ov.w = ok[3] ? acco[i][ct][3] + rch[ct] : 0.f;
            *reinterpret_cast<float4*>(&canvas[(size_t)ch * NPOS_ + (ty0 + yy) * W_ + tx0 + xx]) = ov;
        }
    }
}

extern "C" void kernel_launch(void* const* d_in, const int* in_sizes, int n_in,
                              void* d_out, int out_size, void* d_ws, size_t ws_size,
                              hipStream_t stream) {
    const float* feats = (const float*)d_in[0];
    const int*   coors = (const int*)d_in[1];
    const float* pe    = (const float*)d_in[2];
    const float* wqkv  = (const float*)d_in[3];
    const float* bqkv  = (const float*)d_in[4];
    const float* wout  = (const float*)d_in[5];
    const float* bout  = (const float*)d_in[6];
    float* canvas = (float*)d_out;

    const int n = in_sizes[0] / C_;                           // 200000
    int* grid = (int*)d_ws;                                   // 1 MB
    float* cw = (float*)((char*)d_ws + NPOS_ * sizeof(int));  // 4192 floats

    prep_k<<<273, 256, 0, stream>>>((int4*)grid, wqkv, bqkv, wout, bout, cw);
    build_grid_k<<<(n + 255) / 256, 256, 0, stream>>>(coors, grid, n);
    fused_k<<<(W_ / TX_) * (H_ / TY_), 256, 0, stream>>>(feats, grid, pe, cw, canvas);
}